// Round 1
// baseline (6259.820 us; speedup 1.0000x reference)
//
#include <hip/hip_runtime.h>
#include <math.h>

// Problem constants
constexpr int kB    = 2048;   // batch
constexpr int kA    = 8;      // attrs
constexpr int kEin  = 64;     // input embedding dim
constexpr int kEout = 256;    // output embedding dim
constexpr int kH    = 1024;   // hidden
constexpr int kV    = 1024;   // vocab
constexpr int kL    = 16;     // sequence length
constexpr int kKin  = kA * kEin;      // 512
constexpr int kKg   = kEout + kH;     // 1280

// GEMM tile
constexpr int TBM = 128;
constexpr int TBN = 128;
constexpr int TBK = 16;

__device__ __forceinline__ float sigm(float x) { return 1.0f / (1.0f + expf(-x)); }

// ---------------------------------------------------------------- init state
__global__ __launch_bounds__(256) void init_state(float* __restrict__ c,
                                                  float* __restrict__ emb,
                                                  const float* __restrict__ sos) {
  int i = blockIdx.x * 256 + threadIdx.x;
  if (i < kB * kH) c[i] = 0.0f;
  if (i < kB * kEout) emb[i] = sos[i & (kEout - 1)];
}

// ------------------------------------------------------- h0 = embed @ W_in^T
// A[m,k] gathered on the fly: in_emb[x[m, k/64] * 64 + k%64]
__global__ __launch_bounds__(256) void h0_gemm(const int* __restrict__ x,
                                               const float* __restrict__ in_emb,
                                               const float* __restrict__ W_in,
                                               const float* __restrict__ b_in,
                                               float* __restrict__ h) {
  __shared__ float As[TBK][TBM];
  __shared__ float Bs[TBK][TBN];
  const int t  = threadIdx.x;
  const int tx = t & 15, ty = t >> 4;
  const int r  = t >> 1;
  const int kc = (t & 1) * 8;
  const int m0 = blockIdx.x * TBM;
  const int n0 = blockIdx.y * TBN;
  float acc[8][8] = {};
  for (int k0 = 0; k0 < kKin; k0 += TBK) {
    const int kk   = k0 + kc;
    const int attr = kk >> 6;
    const int e    = kk & 63;
    const int idx  = x[(m0 + r) * kA + attr];
    const float* pa = in_emb + idx * kEin + e;
    float4 a0 = *(const float4*)pa;
    float4 a1 = *(const float4*)(pa + 4);
    const float* pb = W_in + (size_t)(n0 + r) * kKin + kk;
    float4 b0 = *(const float4*)pb;
    float4 b1 = *(const float4*)(pb + 4);
    __syncthreads();
    As[kc+0][r]=a0.x; As[kc+1][r]=a0.y; As[kc+2][r]=a0.z; As[kc+3][r]=a0.w;
    As[kc+4][r]=a1.x; As[kc+5][r]=a1.y; As[kc+6][r]=a1.z; As[kc+7][r]=a1.w;
    Bs[kc+0][r]=b0.x; Bs[kc+1][r]=b0.y; Bs[kc+2][r]=b0.z; Bs[kc+3][r]=b0.w;
    Bs[kc+4][r]=b1.x; Bs[kc+5][r]=b1.y; Bs[kc+6][r]=b1.z; Bs[kc+7][r]=b1.w;
    __syncthreads();
#pragma unroll
    for (int k = 0; k < TBK; ++k) {
      float a[8], b[8];
      *(float4*)&a[0] = *(const float4*)&As[k][ty*8];
      *(float4*)&a[4] = *(const float4*)&As[k][ty*8+4];
      *(float4*)&b[0] = *(const float4*)&Bs[k][tx*8];
      *(float4*)&b[4] = *(const float4*)&Bs[k][tx*8+4];
#pragma unroll
      for (int i = 0; i < 8; ++i)
#pragma unroll
        for (int j = 0; j < 8; ++j)
          acc[i][j] = fmaf(a[i], b[j], acc[i][j]);
    }
  }
#pragma unroll
  for (int i = 0; i < 8; ++i) {
    const int gm = m0 + ty*8 + i;
#pragma unroll
    for (int j = 0; j < 8; ++j) {
      const int gn = n0 + tx*8 + j;
      h[(size_t)gm * kH + gn] = acc[i][j] + b_in[gn];
    }
  }
}

// -------------------------------------- gates = [emb|h] @ [W_ih|W_hh]^T + b,
// fused with LSTM pointwise. N-mapping: local col c = jj*4 + g (gate fastest)
// so each thread owns all 4 gates of its hidden units. Block covers 32 j's.
__global__ __launch_bounds__(256) void gates_lstm(const float* __restrict__ emb,
                                                  const float* __restrict__ h_in,
                                                  const float* __restrict__ W_ih,
                                                  const float* __restrict__ W_hh,
                                                  const float* __restrict__ b_ih,
                                                  const float* __restrict__ b_hh,
                                                  float* __restrict__ c,
                                                  float* __restrict__ h_out) {
  __shared__ float As[TBK][TBM];
  __shared__ float Bs[TBK][TBN];
  const int t  = threadIdx.x;
  const int tx = t & 15, ty = t >> 4;
  const int r  = t >> 1;
  const int kc = (t & 1) * 8;
  const int m0 = blockIdx.x * TBM;
  const int j0 = blockIdx.y * 32;
  // weight row for local col r: gate = r&3, j = j0 + (r>>2)
  const int brow = ((r & 3) << 10) + j0 + (r >> 2);
  float acc[8][8] = {};
  for (int k0 = 0; k0 < kKg; k0 += TBK) {
    const int kk = k0 + kc;
    float4 a0, a1, b0, b1;
    if (kk < kEout) {
      const float* pa = emb + (size_t)(m0 + r) * kEout + kk;
      a0 = *(const float4*)pa; a1 = *(const float4*)(pa + 4);
      const float* pb = W_ih + (size_t)brow * kEout + kk;
      b0 = *(const float4*)pb; b1 = *(const float4*)(pb + 4);
    } else {
      const float* pa = h_in + (size_t)(m0 + r) * kH + (kk - kEout);
      a0 = *(const float4*)pa; a1 = *(const float4*)(pa + 4);
      const float* pb = W_hh + (size_t)brow * kH + (kk - kEout);
      b0 = *(const float4*)pb; b1 = *(const float4*)(pb + 4);
    }
    __syncthreads();
    As[kc+0][r]=a0.x; As[kc+1][r]=a0.y; As[kc+2][r]=a0.z; As[kc+3][r]=a0.w;
    As[kc+4][r]=a1.x; As[kc+5][r]=a1.y; As[kc+6][r]=a1.z; As[kc+7][r]=a1.w;
    Bs[kc+0][r]=b0.x; Bs[kc+1][r]=b0.y; Bs[kc+2][r]=b0.z; Bs[kc+3][r]=b0.w;
    Bs[kc+4][r]=b1.x; Bs[kc+5][r]=b1.y; Bs[kc+6][r]=b1.z; Bs[kc+7][r]=b1.w;
    __syncthreads();
#pragma unroll
    for (int k = 0; k < TBK; ++k) {
      float a[8], b[8];
      *(float4*)&a[0] = *(const float4*)&As[k][ty*8];
      *(float4*)&a[4] = *(const float4*)&As[k][ty*8+4];
      *(float4*)&b[0] = *(const float4*)&Bs[k][tx*8];
      *(float4*)&b[4] = *(const float4*)&Bs[k][tx*8+4];
#pragma unroll
      for (int i = 0; i < 8; ++i)
#pragma unroll
        for (int j = 0; j < 8; ++j)
          acc[i][j] = fmaf(a[i], b[j], acc[i][j]);
    }
  }
  // epilogue: cols tx*8 + jj*4 + g  ->  j = j0 + tx*2 + jj, gates g=0..3
#pragma unroll
  for (int jj = 0; jj < 2; ++jj) {
    const int j = j0 + tx * 2 + jj;
    const float bi = b_ih[j]        + b_hh[j];
    const float bf = b_ih[kH + j]   + b_hh[kH + j];
    const float bg = b_ih[2*kH + j] + b_hh[2*kH + j];
    const float bo = b_ih[3*kH + j] + b_hh[3*kH + j];
#pragma unroll
    for (int i = 0; i < 8; ++i) {
      const int gm = m0 + ty * 8 + i;
      const size_t off = (size_t)gm * kH + j;
      const float ig = acc[i][jj*4+0] + bi;
      const float fg = acc[i][jj*4+1] + bf;
      const float gg = acc[i][jj*4+2] + bg;
      const float og = acc[i][jj*4+3] + bo;
      const float cn = sigm(fg) * c[off] + sigm(ig) * tanhf(gg);
      const float hn = sigm(og) * tanhf(cn);
      c[off] = cn;
      h_out[off] = hn;
    }
  }
}

// ------------------------------------------------ logits = h @ W_out^T + b
__global__ __launch_bounds__(256) void logits_gemm(const float* __restrict__ h,
                                                   const float* __restrict__ W_out,
                                                   const float* __restrict__ b_out,
                                                   float* __restrict__ out) { // out = logits + t*V, row stride L*V
  __shared__ float As[TBK][TBM];
  __shared__ float Bs[TBK][TBN];
  const int t  = threadIdx.x;
  const int tx = t & 15, ty = t >> 4;
  const int r  = t >> 1;
  const int kc = (t & 1) * 8;
  const int m0 = blockIdx.x * TBM;
  const int n0 = blockIdx.y * TBN;
  float acc[8][8] = {};
  for (int k0 = 0; k0 < kH; k0 += TBK) {
    const int kk = k0 + kc;
    const float* pa = h + (size_t)(m0 + r) * kH + kk;
    float4 a0 = *(const float4*)pa;
    float4 a1 = *(const float4*)(pa + 4);
    const float* pb = W_out + (size_t)(n0 + r) * kH + kk;
    float4 b0 = *(const float4*)pb;
    float4 b1 = *(const float4*)(pb + 4);
    __syncthreads();
    As[kc+0][r]=a0.x; As[kc+1][r]=a0.y; As[kc+2][r]=a0.z; As[kc+3][r]=a0.w;
    As[kc+4][r]=a1.x; As[kc+5][r]=a1.y; As[kc+6][r]=a1.z; As[kc+7][r]=a1.w;
    Bs[kc+0][r]=b0.x; Bs[kc+1][r]=b0.y; Bs[kc+2][r]=b0.z; Bs[kc+3][r]=b0.w;
    Bs[kc+4][r]=b1.x; Bs[kc+5][r]=b1.y; Bs[kc+6][r]=b1.z; Bs[kc+7][r]=b1.w;
    __syncthreads();
#pragma unroll
    for (int k = 0; k < TBK; ++k) {
      float a[8], b[8];
      *(float4*)&a[0] = *(const float4*)&As[k][ty*8];
      *(float4*)&a[4] = *(const float4*)&As[k][ty*8+4];
      *(float4*)&b[0] = *(const float4*)&Bs[k][tx*8];
      *(float4*)&b[4] = *(const float4*)&Bs[k][tx*8+4];
#pragma unroll
      for (int i = 0; i < 8; ++i)
#pragma unroll
        for (int j = 0; j < 8; ++j)
          acc[i][j] = fmaf(a[i], b[j], acc[i][j]);
    }
  }
#pragma unroll
  for (int i = 0; i < 8; ++i) {
    const int gm = m0 + ty*8 + i;
#pragma unroll
    for (int j = 0; j < 8; ++j) {
      const int gn = n0 + tx*8 + j;
      out[(size_t)gm * (kL * kV) + gn] = acc[i][j] + b_out[gn];
    }
  }
}

// --------------------------------- argmax (first-max, numpy tie semantics) +
// sequence write + out_emb gather for the next step's input embedding
__global__ __launch_bounds__(256) void argmax_gather(const float* __restrict__ logits_t, // + t*V, row stride L*V
                                                     float* __restrict__ seq,
                                                     const float* __restrict__ out_emb,
                                                     float* __restrict__ emb,
                                                     int t) {
  const int lane = threadIdx.x & 63;
  const int wv   = threadIdx.x >> 6;
  const int b    = blockIdx.x * 4 + wv;
  const float* row = logits_t + (size_t)b * (kL * kV);
  float m = -3.4e38f;
  int  mi = 0;
#pragma unroll
  for (int jr = 0; jr < kV / 64; ++jr) {
    const int idx = jr * 64 + lane;
    const float v = row[idx];
    if (v > m) { m = v; mi = idx; }   // strict > keeps earliest within lane
  }
#pragma unroll
  for (int off = 32; off > 0; off >>= 1) {
    const float om = __shfl_down(m, off);
    const int   oi = __shfl_down(mi, off);
    if (om > m || (om == m && oi < mi)) { m = om; mi = oi; }
  }
  mi = __shfl(mi, 0);
  if (lane == 0) seq[(size_t)b * kL + t] = (float)mi;
  const float4 e = *(const float4*)&out_emb[(size_t)mi * kEout + lane * 4];
  *(float4*)&emb[(size_t)b * kEout + lane * 4] = e;
}

// ---------------------------------------------------------------------------
extern "C" void kernel_launch(void* const* d_in, const int* in_sizes, int n_in,
                              void* d_out, int out_size, void* d_ws, size_t ws_size,
                              hipStream_t stream) {
  const int*   x       = (const int*)d_in[0];
  const float* in_emb  = (const float*)d_in[1];
  const float* out_emb = (const float*)d_in[2];
  const float* W_in    = (const float*)d_in[3];
  const float* b_in    = (const float*)d_in[4];
  const float* W_ih    = (const float*)d_in[5];
  const float* b_ih    = (const float*)d_in[6];
  const float* W_hh    = (const float*)d_in[7];
  const float* b_hh    = (const float*)d_in[8];
  const float* W_out   = (const float*)d_in[9];
  const float* b_out   = (const float*)d_in[10];
  const float* sos     = (const float*)d_in[11];

  float* ws  = (float*)d_ws;                    // 26 MB used
  float* hA  = ws;                              // [B,H]
  float* hB  = ws + (size_t)kB * kH;            // [B,H]
  float* cb  = ws + 2 * (size_t)kB * kH;        // [B,H]
  float* emb = ws + 3 * (size_t)kB * kH;        // [B,EOUT]

  float* seq    = (float*)d_out;                // [B,L]
  float* logits = seq + (size_t)kB * kL;        // [B,L,V]

  init_state<<<(kB * kH + 255) / 256, 256, 0, stream>>>(cb, emb, sos);
  h0_gemm<<<dim3(kB / TBM, kH / TBN), 256, 0, stream>>>(x, in_emb, W_in, b_in, hA);

  for (int t = 0; t < kL; ++t) {
    const float* hin = (t & 1) ? hB : hA;
    float*      hout = (t & 1) ? hA : hB;
    gates_lstm<<<dim3(kB / TBM, kH / 32), 256, 0, stream>>>(emb, hin, W_ih, W_hh, b_ih, b_hh, cb, hout);
    logits_gemm<<<dim3(kB / TBM, kV / TBN), 256, 0, stream>>>(hout, W_out, b_out, logits + (size_t)t * kV);
    argmax_gather<<<kB / 4, 256, 0, stream>>>(logits + (size_t)t * kV, seq, out_emb, emb, t);
  }
}

// Round 3
// 2342.200 us; speedup vs baseline: 2.6726x; 2.6726x over previous
//
#include <hip/hip_runtime.h>
#include <math.h>

// Problem constants
constexpr int kB    = 2048;
constexpr int kA    = 8;
constexpr int kEin  = 64;
constexpr int kEout = 256;
constexpr int kH    = 1024;
constexpr int kV    = 1024;
constexpr int kL    = 16;
constexpr int kKin  = kA * kEin;      // 512
constexpr int kKg   = kEout + kH;     // 1280
constexpr float kInvLo = 1.0f / 2048.0f;

using half8 = __attribute__((ext_vector_type(8))) _Float16;
using half4 = __attribute__((ext_vector_type(4))) _Float16;
using f32x4 = __attribute__((ext_vector_type(4))) float;

__device__ __forceinline__ float sigm(float x) { return 1.0f / (1.0f + expf(-x)); }

// fp32 -> fp16 hi + fp16 lo (x ~= hi + lo/2048), ~22 significant bits
struct HL { _Float16 hi, lo; };
__device__ __forceinline__ HL split2v(float x) {
  HL r;
  r.hi = (_Float16)x;
  r.lo = (_Float16)((x - (float)r.hi) * 2048.0f);
  return r;
}

// ---------------------------------------------------------------- init state
__global__ __launch_bounds__(256) void init_state(float* __restrict__ c,
                                                  _Float16* __restrict__ emb_hi,
                                                  _Float16* __restrict__ emb_lo,
                                                  const float* __restrict__ sos) {
  int i = blockIdx.x * 256 + threadIdx.x;
  c[i] = 0.0f;
  if (i < kB * kEout) {
    HL s = split2v(sos[i & (kEout - 1)]);
    emb_hi[i] = s.hi; emb_lo[i] = s.lo;
  }
}

// -------------------------------------------------- plain fp32 -> hi/lo split
__global__ __launch_bounds__(256) void split_plain(const float* __restrict__ src,
                                                   _Float16* __restrict__ hi,
                                                   _Float16* __restrict__ lo,
                                                   int n4) {
  int i = blockIdx.x * 256 + threadIdx.x;
  if (i >= n4) return;
  float4 v = ((const float4*)src)[i];
  half4 h, l;
  HL s0 = split2v(v.x), s1 = split2v(v.y), s2 = split2v(v.z), s3 = split2v(v.w);
  h.x = s0.hi; l.x = s0.lo; h.y = s1.hi; l.y = s1.lo;
  h.z = s2.hi; l.z = s2.lo; h.w = s3.hi; l.w = s3.lo;
  *(half4*)(hi + (size_t)i * 4) = h;
  *(half4*)(lo + (size_t)i * 4) = l;
}

// ------------------------- gates weights: concat [W_ih|W_hh], gate-permute, split
// output row n <-> gate=(n>>4)&3, j=((n>>6)<<4)|(n&15); source row = gate*1024+j
__global__ __launch_bounds__(320) void split_gates_w(const float* __restrict__ W_ih,
                                                     const float* __restrict__ W_hh,
                                                     _Float16* __restrict__ hi,
                                                     _Float16* __restrict__ lo) {
  const int n  = blockIdx.x;
  const int k4 = threadIdx.x * 4;
  const int g  = (n >> 4) & 3;
  const int j  = ((n >> 6) << 4) | (n & 15);
  const int src = g * kH + j;
  float4 v = (k4 < kEout) ? *(const float4*)&W_ih[(size_t)src * kEout + k4]
                          : *(const float4*)&W_hh[(size_t)src * kH + (k4 - kEout)];
  half4 h, l;
  HL s0 = split2v(v.x), s1 = split2v(v.y), s2 = split2v(v.z), s3 = split2v(v.w);
  h.x = s0.hi; l.x = s0.lo; h.y = s1.hi; l.y = s1.lo;
  h.z = s2.hi; l.z = s2.lo; h.w = s3.hi; l.w = s3.lo;
  *(half4*)(hi + (size_t)n * kKg + k4) = h;
  *(half4*)(lo + (size_t)n * kKg + k4) = l;
}

// ------------------------------------------------------- h0 = embed @ W_in^T
// fp32 vector GEMM (runs once); epilogue emits split h0
__global__ __launch_bounds__(256) void h0_gemm(const int* __restrict__ x,
                                               const float* __restrict__ in_emb,
                                               const float* __restrict__ W_in,
                                               const float* __restrict__ b_in,
                                               _Float16* __restrict__ h_hi,
                                               _Float16* __restrict__ h_lo) {
  __shared__ float As[16][128];
  __shared__ float Bs[16][128];
  const int t  = threadIdx.x;
  const int tx = t & 15, ty = t >> 4;
  const int r  = t >> 1;
  const int kc = (t & 1) * 8;
  const int m0 = blockIdx.x * 128;
  const int n0 = blockIdx.y * 128;
  float acc[8][8] = {};
  for (int k0 = 0; k0 < kKin; k0 += 16) {
    const int kk   = k0 + kc;
    const int attr = kk >> 6;
    const int e    = kk & 63;
    const int idx  = x[(m0 + r) * kA + attr];
    const float* pa = in_emb + (size_t)idx * kEin + e;
    float4 a0 = *(const float4*)pa;
    float4 a1 = *(const float4*)(pa + 4);
    const float* pb = W_in + (size_t)(n0 + r) * kKin + kk;
    float4 b0 = *(const float4*)pb;
    float4 b1 = *(const float4*)(pb + 4);
    __syncthreads();
    As[kc+0][r]=a0.x; As[kc+1][r]=a0.y; As[kc+2][r]=a0.z; As[kc+3][r]=a0.w;
    As[kc+4][r]=a1.x; As[kc+5][r]=a1.y; As[kc+6][r]=a1.z; As[kc+7][r]=a1.w;
    Bs[kc+0][r]=b0.x; Bs[kc+1][r]=b0.y; Bs[kc+2][r]=b0.z; Bs[kc+3][r]=b0.w;
    Bs[kc+4][r]=b1.x; Bs[kc+5][r]=b1.y; Bs[kc+6][r]=b1.z; Bs[kc+7][r]=b1.w;
    __syncthreads();
#pragma unroll
    for (int k = 0; k < 16; ++k) {
      float a[8], b[8];
      *(float4*)&a[0] = *(const float4*)&As[k][ty*8];
      *(float4*)&a[4] = *(const float4*)&As[k][ty*8+4];
      *(float4*)&b[0] = *(const float4*)&Bs[k][tx*8];
      *(float4*)&b[4] = *(const float4*)&Bs[k][tx*8+4];
#pragma unroll
      for (int i = 0; i < 8; ++i)
#pragma unroll
        for (int j = 0; j < 8; ++j)
          acc[i][j] = fmaf(a[i], b[j], acc[i][j]);
    }
  }
#pragma unroll
  for (int i = 0; i < 8; ++i) {
    const int gm = m0 + ty*8 + i;
#pragma unroll
    for (int j = 0; j < 8; ++j) {
      const int gn = n0 + tx*8 + j;
      HL s = split2v(acc[i][j] + b_in[gn]);
      h_hi[(size_t)gm * kH + gn] = s.hi;
      h_lo[(size_t)gm * kH + gn] = s.lo;
    }
  }
}

// --------------------- gates GEMM (fp16x2 MFMA, 3 passes) + fused LSTM pointwise
// A[m, 0..1280) = [emb | h] (split), B = gate-permuted split weights.
// Block 128x128, 4 waves (2x2), wave 64x64 = 4x4 16x16x32 fragments.
// N mapping: fragment nf = gate, wave col lc -> hidden unit j.
__global__ __launch_bounds__(256, 2) void gates_lstm_mfma(
    const _Float16* __restrict__ emb_hi, const _Float16* __restrict__ emb_lo,
    const _Float16* __restrict__ h_hi,   const _Float16* __restrict__ h_lo,
    const _Float16* __restrict__ Wg_hi,  const _Float16* __restrict__ Wg_lo,
    const float* __restrict__ b_ih, const float* __restrict__ b_hh,
    float* __restrict__ c,
    _Float16* __restrict__ ho_hi, _Float16* __restrict__ ho_lo) {
  __shared__ _Float16 Ah[4][128][8], Al[4][128][8], Bh[4][128][8], Bl[4][128][8];
  const int t    = threadIdx.x;
  const int m0   = blockIdx.x * 128;
  const int by   = blockIdx.y;
  const int n0   = by * 128;
  const int r    = t & 127, q = t >> 7;       // staging: row, k-half
  const int lane = t & 63,  wid = t >> 6;
  const int wm   = (wid >> 1) * 64;           // wave m offset
  const int wnv  = wid & 1;                   // wave n index
  const int lc   = lane & 15, lg = lane >> 4;
  f32x4 acc1[4][4] = {}; f32x4 acc2[4][4] = {};
  for (int k0 = 0; k0 < kKg; k0 += 32) {
    const _Float16 *pah, *pal;
    if (k0 < kEout) {
      size_t o = (size_t)(m0 + r) * kEout + k0 + q * 16;
      pah = emb_hi + o; pal = emb_lo + o;
    } else {
      size_t o = (size_t)(m0 + r) * kH + (k0 - kEout) + q * 16;
      pah = h_hi + o; pal = h_lo + o;
    }
    half8 a0 = *(const half8*)pah,        a1 = *(const half8*)(pah + 8);
    half8 a2 = *(const half8*)pal,        a3 = *(const half8*)(pal + 8);
    size_t ob = (size_t)(n0 + r) * kKg + k0 + q * 16;
    half8 b0 = *(const half8*)(Wg_hi + ob), b1 = *(const half8*)(Wg_hi + ob + 8);
    half8 b2 = *(const half8*)(Wg_lo + ob), b3 = *(const half8*)(Wg_lo + ob + 8);
    __syncthreads();
    *(half8*)&Ah[2*q  ][r][0] = a0; *(half8*)&Ah[2*q+1][r][0] = a1;
    *(half8*)&Al[2*q  ][r][0] = a2; *(half8*)&Al[2*q+1][r][0] = a3;
    *(half8*)&Bh[2*q  ][r][0] = b0; *(half8*)&Bh[2*q+1][r][0] = b1;
    *(half8*)&Bl[2*q  ][r][0] = b2; *(half8*)&Bl[2*q+1][r][0] = b3;
    __syncthreads();
    half8 ah[4], al[4], bh[4], bl[4];
#pragma unroll
    for (int mf = 0; mf < 4; ++mf) {
      ah[mf] = *(const half8*)&Ah[lg][wm + mf*16 + lc][0];
      al[mf] = *(const half8*)&Al[lg][wm + mf*16 + lc][0];
    }
#pragma unroll
    for (int nf = 0; nf < 4; ++nf) {
      bh[nf] = *(const half8*)&Bh[lg][wnv*64 + nf*16 + lc][0];
      bl[nf] = *(const half8*)&Bl[lg][wnv*64 + nf*16 + lc][0];
    }
#pragma unroll
    for (int mf = 0; mf < 4; ++mf)
#pragma unroll
      for (int nf = 0; nf < 4; ++nf) {
        acc1[mf][nf] = __builtin_amdgcn_mfma_f32_16x16x32_f16(ah[mf], bh[nf], acc1[mf][nf], 0, 0, 0);
        acc2[mf][nf] = __builtin_amdgcn_mfma_f32_16x16x32_f16(ah[mf], bl[nf], acc2[mf][nf], 0, 0, 0);
        acc2[mf][nf] = __builtin_amdgcn_mfma_f32_16x16x32_f16(al[mf], bh[nf], acc2[mf][nf], 0, 0, 0);
      }
  }
  // epilogue: lane's column j; 4 n-fragments = 4 gates (i,f,g,o)
  const int j = by * 32 + wnv * 16 + lc;
  float bb[4];
#pragma unroll
  for (int nf = 0; nf < 4; ++nf) bb[nf] = b_ih[nf * kH + j] + b_hh[nf * kH + j];
#pragma unroll
  for (int mf = 0; mf < 4; ++mf)
#pragma unroll
    for (int reg = 0; reg < 4; ++reg) {
      const int m = m0 + wm + mf * 16 + lg * 4 + reg;
      const size_t off = (size_t)m * kH + j;
      const float vi = acc1[mf][0][reg] + acc2[mf][0][reg] * kInvLo + bb[0];
      const float vf = acc1[mf][1][reg] + acc2[mf][1][reg] * kInvLo + bb[1];
      const float vg = acc1[mf][2][reg] + acc2[mf][2][reg] * kInvLo + bb[2];
      const float vo = acc1[mf][3][reg] + acc2[mf][3][reg] * kInvLo + bb[3];
      const float cn = sigm(vf) * c[off] + sigm(vi) * tanhf(vg);
      const float hn = sigm(vo) * tanhf(cn);
      c[off] = cn;
      HL s = split2v(hn);
      ho_hi[off] = s.hi; ho_lo[off] = s.lo;
    }
}

// ----------------------------- logits = h @ W_out^T + b (fp16x2 MFMA, 3 passes)
// Block 128x64 (grid 16x16 = 256 blocks), 4 waves, wave 32x64 = 2x4 fragments.
__global__ __launch_bounds__(256, 2) void logits_mfma(
    const _Float16* __restrict__ h_hi, const _Float16* __restrict__ h_lo,
    const _Float16* __restrict__ Wo_hi, const _Float16* __restrict__ Wo_lo,
    const float* __restrict__ b_out, float* __restrict__ out) {
  __shared__ _Float16 Ah[4][128][8], Al[4][128][8], Bh[4][64][8], Bl[4][64][8];
  const int t    = threadIdx.x;
  const int m0   = blockIdx.x * 128, n0 = blockIdx.y * 64;
  const int lane = t & 63, wid = t >> 6;
  const int lc   = lane & 15, lg = lane >> 4;
  const int wm   = wid * 32;
  const int rA   = t & 127, qA = t >> 7;
  const int rB   = t & 63,  gB = t >> 6;
  f32x4 acc1[2][4] = {}; f32x4 acc2[2][4] = {};
  for (int k0 = 0; k0 < kH; k0 += 32) {
    size_t oa = (size_t)(m0 + rA) * kH + k0 + qA * 16;
    half8 a0 = *(const half8*)(h_hi + oa), a1 = *(const half8*)(h_hi + oa + 8);
    half8 a2 = *(const half8*)(h_lo + oa), a3 = *(const half8*)(h_lo + oa + 8);
    size_t obo = (size_t)(n0 + rB) * kH + k0 + gB * 8;
    half8 b0 = *(const half8*)(Wo_hi + obo);
    half8 b1 = *(const half8*)(Wo_lo + obo);
    __syncthreads();
    *(half8*)&Ah[2*qA  ][rA][0] = a0; *(half8*)&Ah[2*qA+1][rA][0] = a1;
    *(half8*)&Al[2*qA  ][rA][0] = a2; *(half8*)&Al[2*qA+1][rA][0] = a3;
    *(half8*)&Bh[gB][rB][0] = b0;     *(half8*)&Bl[gB][rB][0] = b1;
    __syncthreads();
    half8 ah[2], al[2], bh[4], bl[4];
#pragma unroll
    for (int mf = 0; mf < 2; ++mf) {
      ah[mf] = *(const half8*)&Ah[lg][wm + mf*16 + lc][0];
      al[mf] = *(const half8*)&Al[lg][wm + mf*16 + lc][0];
    }
#pragma unroll
    for (int nf = 0; nf < 4; ++nf) {
      bh[nf] = *(const half8*)&Bh[lg][nf*16 + lc][0];
      bl[nf] = *(const half8*)&Bl[lg][nf*16 + lc][0];
    }
#pragma unroll
    for (int mf = 0; mf < 2; ++mf)
#pragma unroll
      for (int nf = 0; nf < 4; ++nf) {
        acc1[mf][nf] = __builtin_amdgcn_mfma_f32_16x16x32_f16(ah[mf], bh[nf], acc1[mf][nf], 0, 0, 0);
        acc2[mf][nf] = __builtin_amdgcn_mfma_f32_16x16x32_f16(ah[mf], bl[nf], acc2[mf][nf], 0, 0, 0);
        acc2[mf][nf] = __builtin_amdgcn_mfma_f32_16x16x32_f16(al[mf], bh[nf], acc2[mf][nf], 0, 0, 0);
      }
  }
#pragma unroll
  for (int mf = 0; mf < 2; ++mf)
#pragma unroll
    for (int reg = 0; reg < 4; ++reg) {
      const int m = m0 + wm + mf * 16 + lg * 4 + reg;
#pragma unroll
      for (int nf = 0; nf < 4; ++nf) {
        const int n = n0 + nf * 16 + lc;
        out[(size_t)m * (kL * kV) + n] = acc1[mf][nf][reg] + acc2[mf][nf][reg] * kInvLo + b_out[n];
      }
    }
}

// --------------------------------- argmax (first-max) + seq write + emb gather
__global__ __launch_bounds__(256) void argmax_gather(const float* __restrict__ logits_t,
                                                     float* __restrict__ seq,
                                                     const _Float16* __restrict__ oemb_hi,
                                                     const _Float16* __restrict__ oemb_lo,
                                                     _Float16* __restrict__ emb_hi,
                                                     _Float16* __restrict__ emb_lo,
                                                     int t) {
  const int lane = threadIdx.x & 63;
  const int wv   = threadIdx.x >> 6;
  const int b    = blockIdx.x * 4 + wv;
  const float* row = logits_t + (size_t)b * (kL * kV);
  float m = -3.4e38f;
  int  mi = 0;
#pragma unroll
  for (int jr = 0; jr < kV / 64; ++jr) {
    const int idx = jr * 64 + lane;
    const float v = row[idx];
    if (v > m) { m = v; mi = idx; }
  }
#pragma unroll
  for (int off = 32; off > 0; off >>= 1) {
    const float om = __shfl_down(m, off);
    const int   oi = __shfl_down(mi, off);
    if (om > m || (om == m && oi < mi)) { m = om; mi = oi; }
  }
  mi = __shfl(mi, 0);
  if (lane == 0) seq[(size_t)b * kL + t] = (float)mi;
  const half4 eh = *(const half4*)&oemb_hi[(size_t)mi * kEout + lane * 4];
  const half4 el = *(const half4*)&oemb_lo[(size_t)mi * kEout + lane * 4];
  *(half4*)&emb_hi[(size_t)b * kEout + lane * 4] = eh;
  *(half4*)&emb_lo[(size_t)b * kEout + lane * 4] = el;
}

// ---------------------------------------------------------------------------
extern "C" void kernel_launch(void* const* d_in, const int* in_sizes, int n_in,
                              void* d_out, int out_size, void* d_ws, size_t ws_size,
                              hipStream_t stream) {
  const int*   x       = (const int*)d_in[0];
  const float* in_emb  = (const float*)d_in[1];
  const float* out_emb = (const float*)d_in[2];
  const float* W_in    = (const float*)d_in[3];
  const float* b_in    = (const float*)d_in[4];
  const float* W_ih    = (const float*)d_in[5];
  const float* b_ih    = (const float*)d_in[6];
  const float* W_hh    = (const float*)d_in[7];
  const float* b_hh    = (const float*)d_in[8];
  const float* W_out   = (const float*)d_in[9];
  const float* b_out   = (const float*)d_in[10];
  const float* sos     = (const float*)d_in[11];

  // workspace layout
  float* cb = (float*)d_ws;                            // [B,H] fp32 cell state
  _Float16* hp = (_Float16*)(cb + (size_t)kB * kH);
  const size_t nBH = (size_t)kB * kH;                  // 2097152
  _Float16* hA_hi  = hp;            _Float16* hA_lo  = hp + nBH;
  _Float16* hB_hi  = hp + 2*nBH;    _Float16* hB_lo  = hp + 3*nBH;
  _Float16* emb_hi = hp + 4*nBH;    _Float16* emb_lo = emb_hi + (size_t)kB*kEout;
  _Float16* Wg_hi  = emb_lo + (size_t)kB*kEout;
  _Float16* Wg_lo  = Wg_hi + (size_t)4*kH*kKg;         // 5242880 each
  _Float16* Wo_hi  = Wg_lo + (size_t)4*kH*kKg;
  _Float16* Wo_lo  = Wo_hi + (size_t)kV*kH;
  _Float16* oe_hi  = Wo_lo + (size_t)kV*kH;
  _Float16* oe_lo  = oe_hi + (size_t)kV*kEout;

  float* seq    = (float*)d_out;                       // [B,L]
  float* logits = seq + (size_t)kB * kL;               // [B,L,V]

  init_state<<<(kB * kH) / 256, 256, 0, stream>>>(cb, emb_hi, emb_lo, sos);
  split_gates_w<<<4 * kH, 320, 0, stream>>>(W_ih, W_hh, Wg_hi, Wg_lo);
  split_plain<<<(kV * kH / 4) / 256, 256, 0, stream>>>(W_out, Wo_hi, Wo_lo, kV * kH / 4);
  split_plain<<<(kV * kEout / 4) / 256, 256, 0, stream>>>(out_emb, oe_hi, oe_lo, kV * kEout / 4);
  h0_gemm<<<dim3(kB / 128, kH / 128), 256, 0, stream>>>(x, in_emb, W_in, b_in, hA_hi, hA_lo);

  for (int t = 0; t < kL; ++t) {
    const _Float16* hi_h = (t & 1) ? hB_hi : hA_hi;
    const _Float16* hi_l = (t & 1) ? hB_lo : hA_lo;
    _Float16* ho_h = (t & 1) ? hA_hi : hB_hi;
    _Float16* ho_l = (t & 1) ? hA_lo : hB_lo;
    gates_lstm_mfma<<<dim3(kB / 128, (4 * kH) / 128), 256, 0, stream>>>(
        emb_hi, emb_lo, hi_h, hi_l, Wg_hi, Wg_lo, b_ih, b_hh, cb, ho_h, ho_l);
    logits_mfma<<<dim3(kB / 128, kV / 64), 256, 0, stream>>>(
        ho_h, ho_l, Wo_hi, Wo_lo, b_out, logits + (size_t)t * kV);
    argmax_gather<<<kB / 4, 256, 0, stream>>>(logits + (size_t)t * kV, seq,
                                              oe_hi, oe_lo, emb_hi, emb_lo, t);
  }
}

// Round 4
// 2319.520 us; speedup vs baseline: 2.6988x; 1.0098x over previous
//
#include <hip/hip_runtime.h>
#include <math.h>

// Problem constants
constexpr int kB    = 2048;
constexpr int kA    = 8;
constexpr int kEin  = 64;
constexpr int kEout = 256;
constexpr int kH    = 1024;
constexpr int kV    = 1024;
constexpr int kL    = 16;
constexpr int kKin  = kA * kEin;      // 512
constexpr int kKg   = kEout + kH;     // 1280
constexpr float kInvLo = 1.0f / 2048.0f;

using half8 = __attribute__((ext_vector_type(8))) _Float16;
using half4 = __attribute__((ext_vector_type(4))) _Float16;
using f32x4 = __attribute__((ext_vector_type(4))) float;

// async global->LDS, 16B per lane; lds base must be wave-uniform, dest = base + lane*16
#define GLL16(g, l) __builtin_amdgcn_global_load_lds(                        \
    (const __attribute__((address_space(1))) void*)(g),                      \
    (__attribute__((address_space(3))) void*)(l), 16, 0, 0)

__device__ __forceinline__ float sigm(float x) { return 1.0f / (1.0f + expf(-x)); }

// fp32 -> fp16 hi + fp16 lo (x ~= hi + lo/2048), ~22 significant bits
struct HL { _Float16 hi, lo; };
__device__ __forceinline__ HL split2v(float x) {
  HL r;
  r.hi = (_Float16)x;
  r.lo = (_Float16)((x - (float)r.hi) * 2048.0f);
  return r;
}

// ---------------------------------------------------------------- init state
__global__ __launch_bounds__(256) void init_state(float* __restrict__ c,
                                                  _Float16* __restrict__ emb_hi,
                                                  _Float16* __restrict__ emb_lo,
                                                  const float* __restrict__ sos) {
  int i = blockIdx.x * 256 + threadIdx.x;
  c[i] = 0.0f;
  if (i < kB * kEout) {
    HL s = split2v(sos[i & (kEout - 1)]);
    emb_hi[i] = s.hi; emb_lo[i] = s.lo;
  }
}

// -------------------------------------------------- plain fp32 -> hi/lo split
__global__ __launch_bounds__(256) void split_plain(const float* __restrict__ src,
                                                   _Float16* __restrict__ hi,
                                                   _Float16* __restrict__ lo,
                                                   int n4) {
  int i = blockIdx.x * 256 + threadIdx.x;
  if (i >= n4) return;
  float4 v = ((const float4*)src)[i];
  half4 h, l;
  HL s0 = split2v(v.x), s1 = split2v(v.y), s2 = split2v(v.z), s3 = split2v(v.w);
  h.x = s0.hi; l.x = s0.lo; h.y = s1.hi; l.y = s1.lo;
  h.z = s2.hi; l.z = s2.lo; h.w = s3.hi; l.w = s3.lo;
  *(half4*)(hi + (size_t)i * 4) = h;
  *(half4*)(lo + (size_t)i * 4) = l;
}

// ------------------------- gates weights: concat [W_ih|W_hh], gate-permute, split
// output row n <-> gate=(n>>4)&3, j=((n>>6)<<4)|(n&15); source row = gate*1024+j
__global__ __launch_bounds__(320) void split_gates_w(const float* __restrict__ W_ih,
                                                     const float* __restrict__ W_hh,
                                                     _Float16* __restrict__ hi,
                                                     _Float16* __restrict__ lo) {
  const int n  = blockIdx.x;
  const int k4 = threadIdx.x * 4;
  const int g  = (n >> 4) & 3;
  const int j  = ((n >> 6) << 4) | (n & 15);
  const int src = g * kH + j;
  float4 v = (k4 < kEout) ? *(const float4*)&W_ih[(size_t)src * kEout + k4]
                          : *(const float4*)&W_hh[(size_t)src * kH + (k4 - kEout)];
  half4 h, l;
  HL s0 = split2v(v.x), s1 = split2v(v.y), s2 = split2v(v.z), s3 = split2v(v.w);
  h.x = s0.hi; l.x = s0.lo; h.y = s1.hi; l.y = s1.lo;
  h.z = s2.hi; l.z = s2.lo; h.w = s3.hi; l.w = s3.lo;
  *(half4*)(hi + (size_t)n * kKg + k4) = h;
  *(half4*)(lo + (size_t)n * kKg + k4) = l;
}

// ------------------------------------------------------- h0 = embed @ W_in^T
// fp32 vector GEMM (runs once); epilogue emits split h0
__global__ __launch_bounds__(256) void h0_gemm(const int* __restrict__ x,
                                               const float* __restrict__ in_emb,
                                               const float* __restrict__ W_in,
                                               const float* __restrict__ b_in,
                                               _Float16* __restrict__ h_hi,
                                               _Float16* __restrict__ h_lo) {
  __shared__ float As[16][128];
  __shared__ float Bs[16][128];
  const int t  = threadIdx.x;
  const int tx = t & 15, ty = t >> 4;
  const int r  = t >> 1;
  const int kc = (t & 1) * 8;
  const int m0 = blockIdx.x * 128;
  const int n0 = blockIdx.y * 128;
  float acc[8][8] = {};
  for (int k0 = 0; k0 < kKin; k0 += 16) {
    const int kk   = k0 + kc;
    const int attr = kk >> 6;
    const int e    = kk & 63;
    const int idx  = x[(m0 + r) * kA + attr];
    const float* pa = in_emb + (size_t)idx * kEin + e;
    float4 a0 = *(const float4*)pa;
    float4 a1 = *(const float4*)(pa + 4);
    const float* pb = W_in + (size_t)(n0 + r) * kKin + kk;
    float4 b0 = *(const float4*)pb;
    float4 b1 = *(const float4*)(pb + 4);
    __syncthreads();
    As[kc+0][r]=a0.x; As[kc+1][r]=a0.y; As[kc+2][r]=a0.z; As[kc+3][r]=a0.w;
    As[kc+4][r]=a1.x; As[kc+5][r]=a1.y; As[kc+6][r]=a1.z; As[kc+7][r]=a1.w;
    Bs[kc+0][r]=b0.x; Bs[kc+1][r]=b0.y; Bs[kc+2][r]=b0.z; Bs[kc+3][r]=b0.w;
    Bs[kc+4][r]=b1.x; Bs[kc+5][r]=b1.y; Bs[kc+6][r]=b1.z; Bs[kc+7][r]=b1.w;
    __syncthreads();
#pragma unroll
    for (int k = 0; k < 16; ++k) {
      float a[8], b[8];
      *(float4*)&a[0] = *(const float4*)&As[k][ty*8];
      *(float4*)&a[4] = *(const float4*)&As[k][ty*8+4];
      *(float4*)&b[0] = *(const float4*)&Bs[k][tx*8];
      *(float4*)&b[4] = *(const float4*)&Bs[k][tx*8+4];
#pragma unroll
      for (int i = 0; i < 8; ++i)
#pragma unroll
        for (int j = 0; j < 8; ++j)
          acc[i][j] = fmaf(a[i], b[j], acc[i][j]);
    }
  }
#pragma unroll
  for (int i = 0; i < 8; ++i) {
    const int gm = m0 + ty*8 + i;
#pragma unroll
    for (int j = 0; j < 8; ++j) {
      const int gn = n0 + tx*8 + j;
      HL s = split2v(acc[i][j] + b_in[gn]);
      h_hi[(size_t)gm * kH + gn] = s.hi;
      h_lo[(size_t)gm * kH + gn] = s.lo;
    }
  }
}

// --------------------- gates GEMM (fp16x2 MFMA, 3 passes) + fused LSTM pointwise
// A[m, 0..1280) = [emb | h] (split), B = gate-permuted split weights.
// Block 128x128, 4 waves (2x2), wave 64x64 = 4x4 16x16x32 fragments.
// Staging via global_load_lds width=16: each wave writes a contiguous 1KB
// half-slab (wave-uniform base + lane*16).
__global__ __launch_bounds__(256, 2) void gates_lstm_mfma(
    const _Float16* __restrict__ emb_hi, const _Float16* __restrict__ emb_lo,
    const _Float16* __restrict__ h_hi,   const _Float16* __restrict__ h_lo,
    const _Float16* __restrict__ Wg_hi,  const _Float16* __restrict__ Wg_lo,
    const float* __restrict__ b_ih, const float* __restrict__ b_hh,
    float* __restrict__ c,
    _Float16* __restrict__ ho_hi, _Float16* __restrict__ ho_lo) {
  __shared__ __align__(16) _Float16 Ah[4][128][8], Al[4][128][8], Bh[4][128][8], Bl[4][128][8];
  const int t    = threadIdx.x;
  const int m0   = blockIdx.x * 128;
  const int by   = blockIdx.y;
  const int n0   = by * 128;
  const int r    = t & 127, q = t >> 7;       // staging: row, k-half
  const int rw   = r & 64;                     // wave-uniform row base
  const int lane = t & 63,  wid = t >> 6;
  const int wm   = (wid >> 1) * 64;           // wave m offset
  const int wnv  = wid & 1;                   // wave n index
  const int lc   = lane & 15, lg = lane >> 4;
  f32x4 acc1[4][4] = {}; f32x4 acc2[4][4] = {};
  for (int k0 = 0; k0 < kKg; k0 += 32) {
    const _Float16 *pah, *pal;
    if (k0 < kEout) {
      size_t o = (size_t)(m0 + r) * kEout + k0 + q * 16;
      pah = emb_hi + o; pal = emb_lo + o;
    } else {
      size_t o = (size_t)(m0 + r) * kH + (k0 - kEout) + q * 16;
      pah = h_hi + o; pal = h_lo + o;
    }
    const size_t ob = (size_t)(n0 + r) * kKg + k0 + q * 16;
    const _Float16* pbh = Wg_hi + ob;
    const _Float16* pbl = Wg_lo + ob;
    __syncthreads();                 // previous iter's fragment reads complete
    GLL16(pah,     &Ah[2*q  ][rw][0]);
    GLL16(pah + 8, &Ah[2*q+1][rw][0]);
    GLL16(pal,     &Al[2*q  ][rw][0]);
    GLL16(pal + 8, &Al[2*q+1][rw][0]);
    GLL16(pbh,     &Bh[2*q  ][rw][0]);
    GLL16(pbh + 8, &Bh[2*q+1][rw][0]);
    GLL16(pbl,     &Bl[2*q  ][rw][0]);
    GLL16(pbl + 8, &Bl[2*q+1][rw][0]);
    __syncthreads();                 // vmcnt(0) drain before barrier -> LDS ready
    half8 ah[4], al[4], bh[4], bl[4];
#pragma unroll
    for (int mf = 0; mf < 4; ++mf) {
      ah[mf] = *(const half8*)&Ah[lg][wm + mf*16 + lc][0];
      al[mf] = *(const half8*)&Al[lg][wm + mf*16 + lc][0];
    }
#pragma unroll
    for (int nf = 0; nf < 4; ++nf) {
      bh[nf] = *(const half8*)&Bh[lg][wnv*64 + nf*16 + lc][0];
      bl[nf] = *(const half8*)&Bl[lg][wnv*64 + nf*16 + lc][0];
    }
#pragma unroll
    for (int mf = 0; mf < 4; ++mf)
#pragma unroll
      for (int nf = 0; nf < 4; ++nf) {
        acc1[mf][nf] = __builtin_amdgcn_mfma_f32_16x16x32_f16(ah[mf], bh[nf], acc1[mf][nf], 0, 0, 0);
        acc2[mf][nf] = __builtin_amdgcn_mfma_f32_16x16x32_f16(ah[mf], bl[nf], acc2[mf][nf], 0, 0, 0);
        acc2[mf][nf] = __builtin_amdgcn_mfma_f32_16x16x32_f16(al[mf], bh[nf], acc2[mf][nf], 0, 0, 0);
      }
  }
  // epilogue: lane's column j; 4 n-fragments = 4 gates (i,f,g,o)
  const int j = by * 32 + wnv * 16 + lc;
  float bb[4];
#pragma unroll
  for (int nf = 0; nf < 4; ++nf) bb[nf] = b_ih[nf * kH + j] + b_hh[nf * kH + j];
#pragma unroll
  for (int mf = 0; mf < 4; ++mf)
#pragma unroll
    for (int reg = 0; reg < 4; ++reg) {
      const int m = m0 + wm + mf * 16 + lg * 4 + reg;
      const size_t off = (size_t)m * kH + j;
      const float vi = acc1[mf][0][reg] + acc2[mf][0][reg] * kInvLo + bb[0];
      const float vf = acc1[mf][1][reg] + acc2[mf][1][reg] * kInvLo + bb[1];
      const float vg = acc1[mf][2][reg] + acc2[mf][2][reg] * kInvLo + bb[2];
      const float vo = acc1[mf][3][reg] + acc2[mf][3][reg] * kInvLo + bb[3];
      const float cn = sigm(vf) * c[off] + sigm(vi) * tanhf(vg);
      const float hn = sigm(vo) * tanhf(cn);
      c[off] = cn;
      HL s = split2v(hn);
      ho_hi[off] = s.hi; ho_lo[off] = s.lo;
    }
}

// ----------------------------- logits = h @ W_out^T + b (fp16x2 MFMA, 3 passes)
// Block 128x64 (grid 16x16 = 256 blocks), 4 waves, wave 32x64 = 2x4 fragments.
__global__ __launch_bounds__(256, 2) void logits_mfma(
    const _Float16* __restrict__ h_hi, const _Float16* __restrict__ h_lo,
    const _Float16* __restrict__ Wo_hi, const _Float16* __restrict__ Wo_lo,
    const float* __restrict__ b_out, float* __restrict__ out) {
  __shared__ __align__(16) _Float16 Ah[4][128][8], Al[4][128][8], Bh[4][64][8], Bl[4][64][8];
  const int t    = threadIdx.x;
  const int m0   = blockIdx.x * 128, n0 = blockIdx.y * 64;
  const int lane = t & 63, wid = t >> 6;
  const int lc   = lane & 15, lg = lane >> 4;
  const int wm   = wid * 32;
  const int rA   = t & 127, qA = t >> 7;
  const int rAw  = rA & 64;                    // wave-uniform
  const int rB   = t & 63,  gB = t >> 6;
  f32x4 acc1[2][4] = {}; f32x4 acc2[2][4] = {};
  for (int k0 = 0; k0 < kH; k0 += 32) {
    const size_t oa  = (size_t)(m0 + rA) * kH + k0 + qA * 16;
    const size_t obo = (size_t)(n0 + rB) * kH + k0 + gB * 8;
    __syncthreads();
    GLL16(h_hi + oa,     &Ah[2*qA  ][rAw][0]);
    GLL16(h_hi + oa + 8, &Ah[2*qA+1][rAw][0]);
    GLL16(h_lo + oa,     &Al[2*qA  ][rAw][0]);
    GLL16(h_lo + oa + 8, &Al[2*qA+1][rAw][0]);
    GLL16(Wo_hi + obo,   &Bh[gB][0][0]);
    GLL16(Wo_lo + obo,   &Bl[gB][0][0]);
    __syncthreads();
    half8 ah[2], al[2], bh[4], bl[4];
#pragma unroll
    for (int mf = 0; mf < 2; ++mf) {
      ah[mf] = *(const half8*)&Ah[lg][wm + mf*16 + lc][0];
      al[mf] = *(const half8*)&Al[lg][wm + mf*16 + lc][0];
    }
#pragma unroll
    for (int nf = 0; nf < 4; ++nf) {
      bh[nf] = *(const half8*)&Bh[lg][nf*16 + lc][0];
      bl[nf] = *(const half8*)&Bl[lg][nf*16 + lc][0];
    }
#pragma unroll
    for (int mf = 0; mf < 2; ++mf)
#pragma unroll
      for (int nf = 0; nf < 4; ++nf) {
        acc1[mf][nf] = __builtin_amdgcn_mfma_f32_16x16x32_f16(ah[mf], bh[nf], acc1[mf][nf], 0, 0, 0);
        acc2[mf][nf] = __builtin_amdgcn_mfma_f32_16x16x32_f16(ah[mf], bl[nf], acc2[mf][nf], 0, 0, 0);
        acc2[mf][nf] = __builtin_amdgcn_mfma_f32_16x16x32_f16(al[mf], bh[nf], acc2[mf][nf], 0, 0, 0);
      }
  }
#pragma unroll
  for (int mf = 0; mf < 2; ++mf)
#pragma unroll
    for (int reg = 0; reg < 4; ++reg) {
      const int m = m0 + wm + mf * 16 + lg * 4 + reg;
#pragma unroll
      for (int nf = 0; nf < 4; ++nf) {
        const int n = n0 + nf * 16 + lc;
        out[(size_t)m * (kL * kV) + n] = acc1[mf][nf][reg] + acc2[mf][nf][reg] * kInvLo + b_out[n];
      }
    }
}

// --------------------------------- argmax (first-max) + seq write + emb gather
__global__ __launch_bounds__(256) void argmax_gather(const float* __restrict__ logits_t,
                                                     float* __restrict__ seq,
                                                     const _Float16* __restrict__ oemb_hi,
                                                     const _Float16* __restrict__ oemb_lo,
                                                     _Float16* __restrict__ emb_hi,
                                                     _Float16* __restrict__ emb_lo,
                                                     int t) {
  const int lane = threadIdx.x & 63;
  const int wv   = threadIdx.x >> 6;
  const int b    = blockIdx.x * 4 + wv;
  const float* row = logits_t + (size_t)b * (kL * kV);
  float m = -3.4e38f;
  int  mi = 0;
#pragma unroll
  for (int jr = 0; jr < kV / 64; ++jr) {
    const int idx = jr * 64 + lane;
    const float v = row[idx];
    if (v > m) { m = v; mi = idx; }
  }
#pragma unroll
  for (int off = 32; off > 0; off >>= 1) {
    const float om = __shfl_down(m, off);
    const int   oi = __shfl_down(mi, off);
    if (om > m || (om == m && oi < mi)) { m = om; mi = oi; }
  }
  mi = __shfl(mi, 0);
  if (lane == 0) seq[(size_t)b * kL + t] = (float)mi;
  const half4 eh = *(const half4*)&oemb_hi[(size_t)mi * kEout + lane * 4];
  const half4 el = *(const half4*)&oemb_lo[(size_t)mi * kEout + lane * 4];
  *(half4*)&emb_hi[(size_t)b * kEout + lane * 4] = eh;
  *(half4*)&emb_lo[(size_t)b * kEout + lane * 4] = el;
}

// ---------------------------------------------------------------------------
extern "C" void kernel_launch(void* const* d_in, const int* in_sizes, int n_in,
                              void* d_out, int out_size, void* d_ws, size_t ws_size,
                              hipStream_t stream) {
  const int*   x       = (const int*)d_in[0];
  const float* in_emb  = (const float*)d_in[1];
  const float* out_emb = (const float*)d_in[2];
  const float* W_in    = (const float*)d_in[3];
  const float* b_in    = (const float*)d_in[4];
  const float* W_ih    = (const float*)d_in[5];
  const float* b_ih    = (const float*)d_in[6];
  const float* W_hh    = (const float*)d_in[7];
  const float* b_hh    = (const float*)d_in[8];
  const float* W_out   = (const float*)d_in[9];
  const float* b_out   = (const float*)d_in[10];
  const float* sos     = (const float*)d_in[11];

  // workspace layout
  float* cb = (float*)d_ws;                            // [B,H] fp32 cell state
  _Float16* hp = (_Float16*)(cb + (size_t)kB * kH);
  const size_t nBH = (size_t)kB * kH;                  // 2097152
  _Float16* hA_hi  = hp;            _Float16* hA_lo  = hp + nBH;
  _Float16* hB_hi  = hp + 2*nBH;    _Float16* hB_lo  = hp + 3*nBH;
  _Float16* emb_hi = hp + 4*nBH;    _Float16* emb_lo = emb_hi + (size_t)kB*kEout;
  _Float16* Wg_hi  = emb_lo + (size_t)kB*kEout;
  _Float16* Wg_lo  = Wg_hi + (size_t)4*kH*kKg;         // 5242880 each
  _Float16* Wo_hi  = Wg_lo + (size_t)4*kH*kKg;
  _Float16* Wo_lo  = Wo_hi + (size_t)kV*kH;
  _Float16* oe_hi  = Wo_lo + (size_t)kV*kH;
  _Float16* oe_lo  = oe_hi + (size_t)kV*kEout;

  float* seq    = (float*)d_out;                       // [B,L]
  float* logits = seq + (size_t)kB * kL;               // [B,L,V]

  init_state<<<(kB * kH) / 256, 256, 0, stream>>>(cb, emb_hi, emb_lo, sos);
  split_gates_w<<<4 * kH, 320, 0, stream>>>(W_ih, W_hh, Wg_hi, Wg_lo);
  split_plain<<<(kV * kH / 4) / 256, 256, 0, stream>>>(W_out, Wo_hi, Wo_lo, kV * kH / 4);
  split_plain<<<(kV * kEout / 4) / 256, 256, 0, stream>>>(out_emb, oe_hi, oe_lo, kV * kEout / 4);
  h0_gemm<<<dim3(kB / 128, kH / 128), 256, 0, stream>>>(x, in_emb, W_in, b_in, hA_hi, hA_lo);

  for (int t = 0; t < kL; ++t) {
    const _Float16* hi_h = (t & 1) ? hB_hi : hA_hi;
    const _Float16* hi_l = (t & 1) ? hB_lo : hA_lo;
    _Float16* ho_h = (t & 1) ? hA_hi : hB_hi;
    _Float16* ho_l = (t & 1) ? hA_lo : hB_lo;
    gates_lstm_mfma<<<dim3(kB / 128, (4 * kH) / 128), 256, 0, stream>>>(
        emb_hi, emb_lo, hi_h, hi_l, Wg_hi, Wg_lo, b_ih, b_hh, cb, ho_h, ho_l);
    logits_mfma<<<dim3(kB / 128, kV / 64), 256, 0, stream>>>(
        ho_h, ho_l, Wo_hi, Wo_lo, b_out, logits + (size_t)t * kV);
    argmax_gather<<<kB / 4, 256, 0, stream>>>(logits + (size_t)t * kV, seq,
                                              oe_hi, oe_lo, emb_hi, emb_lo, t);
  }
}